// Round 1
// baseline (6748.631 us; speedup 1.0000x reference)
//
#include <hip/hip_runtime.h>
#include <cstdint>
#include <cstddef>

#define TT 128
#define BB 32
#define VV 32000
#define EE 1024
#define HH 1024
#define G4 4096   // 4*H

// ---------------- Wh [1024][4096] -> WhT [4096][1024] -----------------------
__global__ __launch_bounds__(256) void k_transpose(const float* __restrict__ Wh,
                                                   float* __restrict__ WhT) {
  __shared__ float tile[32][33];
  int tx = threadIdx.x & 31, ty = threadIdx.x >> 5;   // ty 0..7
  int c0 = blockIdx.x * 32;  // col block in Wh
  int r0 = blockIdx.y * 32;  // row block in Wh
#pragma unroll
  for (int i = 0; i < 4; ++i)
    tile[ty + 8*i][tx] = Wh[(size_t)(r0 + ty + 8*i) * G4 + c0 + tx];
  __syncthreads();
#pragma unroll
  for (int i = 0; i < 4; ++i)
    WhT[(size_t)(c0 + ty + 8*i) * HH + r0 + tx] = tile[tx][ty + 8*i];
}

// ---------------- X_all = gather(emb, tokens) @ Wx + b ----------------------
// M=4096 (t*B+b), K=1024, N=4096. BM=BN=128, BK=8, 256 thr, 8x8 micro.
__global__ __launch_bounds__(256) void k_embed_gemm(
    const int* __restrict__ tokens, const float* __restrict__ emb,
    const float* __restrict__ Wx, const float* __restrict__ bias,
    float* __restrict__ Xall) {
  __shared__ float As[8][128];   // [k][m]
  __shared__ float Bs[8][128];   // [k][n]
  int tid = threadIdx.x;
  int m0 = blockIdx.y * 128, n0 = blockIdx.x * 128;
  int ar = tid >> 1, ak = (tid & 1) * 4;      // A stage: row, k-group
  int bkr = tid >> 5, bnc = (tid & 31) * 4;   // B stage: k-row, col
  int tx = tid & 15, ty = tid >> 4;
  const float* arow = emb + (size_t)tokens[m0 + ar] * EE;
  const float* bptr = Wx + (size_t)bkr * G4 + n0 + bnc;
  float acc[8][8];
#pragma unroll
  for (int i = 0; i < 8; ++i)
#pragma unroll
    for (int j = 0; j < 8; ++j) acc[i][j] = 0.f;
  for (int kb = 0; kb < EE; kb += 8) {
    float4 av = *(const float4*)(arow + kb + ak);
    float4 bv = *(const float4*)(bptr + (size_t)kb * G4);
    __syncthreads();
    As[ak+0][ar] = av.x; As[ak+1][ar] = av.y; As[ak+2][ar] = av.z; As[ak+3][ar] = av.w;
    *(float4*)&Bs[bkr][bnc] = bv;
    __syncthreads();
#pragma unroll
    for (int k = 0; k < 8; ++k) {
      float a[8], bq[8];
      *(float4*)(a)      = *(const float4*)&As[k][ty*8];
      *(float4*)(a + 4)  = *(const float4*)&As[k][ty*8+4];
      *(float4*)(bq)     = *(const float4*)&Bs[k][tx*8];
      *(float4*)(bq + 4) = *(const float4*)&Bs[k][tx*8+4];
#pragma unroll
      for (int i = 0; i < 8; ++i)
#pragma unroll
        for (int j = 0; j < 8; ++j) acc[i][j] = fmaf(a[i], bq[j], acc[i][j]);
    }
  }
#pragma unroll
  for (int i = 0; i < 8; ++i) {
    int m = m0 + ty*8 + i;
#pragma unroll
    for (int j = 0; j < 8; j += 4) {
      int n = n0 + tx*8 + j;
      float4 v;
      v.x = acc[i][j+0] + bias[n+0];
      v.y = acc[i][j+1] + bias[n+1];
      v.z = acc[i][j+2] + bias[n+2];
      v.w = acc[i][j+3] + bias[n+3];
      *(float4*)&Xall[(size_t)m * G4 + n] = v;
    }
  }
}

// ---------------- one LSTM step ---------------------------------------------
// 256 WGs x 512 thr. WG owns 4 h-dims (16 gate cols). thr = (b 0..31, kc 0..15).
__global__ __launch_bounds__(512) void k_lstm_step(
    const float* __restrict__ Xall,   // [4096][4096]
    const float* __restrict__ WhT,    // [4096][1024]
    const float* __restrict__ Hprev,  // [32][1024]
    float* __restrict__ Hout,         // [32][1024]
    float* __restrict__ Cst,          // [32][1024]
    int t) {
  __shared__ float red[16][16][33];   // [c][kc][b]
  __shared__ float gs[4][4][33];      // [gate q][jloc][b]
  int tid = threadIdx.x;
  int j0 = blockIdx.x * 4;
  int b = tid & 31;
  int kc = tid >> 5;                  // 0..15, 64 k's each
  int k0 = kc * 64;
  float acc[16];
#pragma unroll
  for (int c = 0; c < 16; ++c) acc[c] = 0.f;
  const float* hrow = Hprev + b * HH + k0;
  const float* wp[16];
#pragma unroll
  for (int c = 0; c < 16; ++c)
    wp[c] = WhT + (size_t)((c >> 2) * HH + j0 + (c & 3)) * HH + k0;
  for (int kk = 0; kk < 64; kk += 4) {
    float4 hv = *(const float4*)(hrow + kk);
#pragma unroll
    for (int c = 0; c < 16; ++c) {
      float4 wv = *(const float4*)(wp[c] + kk);
      acc[c] = fmaf(hv.x, wv.x, acc[c]);
      acc[c] = fmaf(hv.y, wv.y, acc[c]);
      acc[c] = fmaf(hv.z, wv.z, acc[c]);
      acc[c] = fmaf(hv.w, wv.w, acc[c]);
    }
  }
#pragma unroll
  for (int c = 0; c < 16; ++c) red[c][kc][b] = acc[c];
  __syncthreads();
  // reduce over kc; one thread per (b, c)
  int c2 = tid >> 5;
  float g = 0.f;
#pragma unroll
  for (int r = 0; r < 16; ++r) g += red[c2][r][b];
  int q = c2 >> 2, jl = c2 & 3;
  int gcol = q * HH + j0 + jl;
  g += Xall[(size_t)(t * BB + b) * G4 + gcol];
  float val = (q == 2) ? tanhf(g) : 1.f / (1.f + expf(-g));
  gs[q][jl][b] = val;
  __syncthreads();
  if (tid < 128) {
    int b3 = tid & 31, jl3 = tid >> 5;
    float iv = gs[0][jl3][b3], fv = gs[1][jl3][b3];
    float gv = gs[2][jl3][b3], ov = gs[3][jl3][b3];
    size_t cidx = (size_t)b3 * HH + j0 + jl3;
    float cprev = Cst[cidx];
    float cn = fv * cprev + iv * gv;
    float hn = ov * tanhf(cn);
    Cst[cidx] = cn;
    Hout[cidx] = hn;
  }
}

// ---------------- logits = H_all @ W_h2o + b_o ------------------------------
// M=4096, K=1024, N=32000. Same tiling as embed GEMM.
__global__ __launch_bounds__(256) void k_logits_gemm(
    const float* __restrict__ Hall, const float* __restrict__ W,
    const float* __restrict__ bo, float* __restrict__ out) {
  __shared__ float As[8][128];
  __shared__ float Bs[8][128];
  int tid = threadIdx.x;
  int m0 = blockIdx.y * 128, n0 = blockIdx.x * 128;
  int ar = tid >> 1, ak = (tid & 1) * 4;
  int bkr = tid >> 5, bnc = (tid & 31) * 4;
  int tx = tid & 15, ty = tid >> 4;
  const float* arow = Hall + (size_t)(m0 + ar) * HH;
  const float* bptr = W + (size_t)bkr * VV + n0 + bnc;
  float acc[8][8];
#pragma unroll
  for (int i = 0; i < 8; ++i)
#pragma unroll
    for (int j = 0; j < 8; ++j) acc[i][j] = 0.f;
  for (int kb = 0; kb < HH; kb += 8) {
    float4 av = *(const float4*)(arow + kb + ak);
    float4 bv = *(const float4*)(bptr + (size_t)kb * VV);
    __syncthreads();
    As[ak+0][ar] = av.x; As[ak+1][ar] = av.y; As[ak+2][ar] = av.z; As[ak+3][ar] = av.w;
    *(float4*)&Bs[bkr][bnc] = bv;
    __syncthreads();
#pragma unroll
    for (int k = 0; k < 8; ++k) {
      float a[8], bq[8];
      *(float4*)(a)      = *(const float4*)&As[k][ty*8];
      *(float4*)(a + 4)  = *(const float4*)&As[k][ty*8+4];
      *(float4*)(bq)     = *(const float4*)&Bs[k][tx*8];
      *(float4*)(bq + 4) = *(const float4*)&Bs[k][tx*8+4];
#pragma unroll
      for (int i = 0; i < 8; ++i)
#pragma unroll
        for (int j = 0; j < 8; ++j) acc[i][j] = fmaf(a[i], bq[j], acc[i][j]);
    }
  }
#pragma unroll
  for (int i = 0; i < 8; ++i) {
    int m = m0 + ty*8 + i;
#pragma unroll
    for (int j = 0; j < 8; j += 4) {
      int n = n0 + tx*8 + j;
      float4 v;
      v.x = acc[i][j+0] + bo[n+0];
      v.y = acc[i][j+1] + bo[n+1];
      v.z = acc[i][j+2] + bo[n+2];
      v.w = acc[i][j+3] + bo[n+3];
      *(float4*)&out[(size_t)m * VV + n] = v;
    }
  }
}

extern "C" void kernel_launch(void* const* d_in, const int* in_sizes, int n_in,
                              void* d_out, int out_size, void* d_ws, size_t ws_size,
                              hipStream_t stream) {
  const int*   tokens = (const int*)d_in[0];
  const float* emb    = (const float*)d_in[1];
  const float* Wx     = (const float*)d_in[2];
  const float* Wh     = (const float*)d_in[3];
  const float* bias   = (const float*)d_in[4];
  const float* Wh2o   = (const float*)d_in[5];
  const float* bo     = (const float*)d_in[6];
  float* out = (float*)d_out;

  char* ws = (char*)d_ws;
  // layout: Xall 64MB | Hall 16MB | WhT 16MB | C 128KB | H0 128KB
  float* Xall = (float*)(ws);
  float* Hall = (float*)(ws + 67108864);
  float* WhT  = (float*)(ws + 83886080);
  float* Cst  = (float*)(ws + 100663296);
  float* H0   = (float*)(ws + 100794368);
  if (ws_size < 100925440u) return;  // insufficient workspace

  // zero C state and H0 (harness poisons ws with 0xAA)
  hipMemsetAsync(Cst, 0, 262144, stream);

  dim3 gT(128, 32);
  k_transpose<<<gT, 256, 0, stream>>>(Wh, WhT);

  dim3 g1(32, 32);
  k_embed_gemm<<<g1, 256, 0, stream>>>(tokens, emb, Wx, bias, Xall);

  for (int t = 0; t < TT; ++t) {
    const float* hp = (t == 0) ? H0 : (Hall + (size_t)(t - 1) * BB * HH);
    k_lstm_step<<<256, 512, 0, stream>>>(Xall, WhT, hp,
                                         Hall + (size_t)t * BB * HH, Cst, t);
  }

  dim3 g3(250, 32);
  k_logits_gemm<<<g3, 256, 0, stream>>>(Hall, Wh2o, bo, out);
}